// Round 3
// baseline (113.752 us; speedup 1.0000x reference)
//
#include <hip/hip_runtime.h>

#define LSEQ 8192
#define NF 9
#define CT 4             // tiles per batch
#define TSZ 2048         // tile size
#define NT 512           // threads per block
#define IT 4             // items per thread (NT*IT == TSZ)
#define NW 8             // waves per block
#define EOFF 96          // E[i] = local prefS(t_start - EOFF + i); main x <-> i = x+96
#define EB (TSZ + 184)   // max index used: TSZ+183

__device__ __forceinline__ float f4c(const float4& v, int c) {
    return c == 0 ? v.x : c == 1 ? v.y : c == 2 ? v.z : v.w;
}

__device__ __forceinline__ double block_scan(double tot, int lane, int wid,
                                             double* swv, double* blockTot) {
    double v = tot;
    #pragma unroll
    for (int off = 1; off < 64; off <<= 1) {
        double n = __shfl_up(v, (unsigned)off, 64);
        if (lane >= off) v += n;
    }
    if (lane == 63) swv[wid] = v;
    __syncthreads();
    double wOff = 0.0, bTot = 0.0;
    #pragma unroll
    for (int w = 0; w < NW; ++w) {
        double t2 = swv[w];
        if (w < wid) wOff += t2;
        bTot += t2;
    }
    __syncthreads();
    *blockTot = bTot;
    return wOff + (v - tot);
}

__global__ __launch_bounds__(NT, 4) void kenneth_fused(const float* __restrict__ conc,
                                                       const float* __restrict__ kern,
                                                       unsigned long long* __restrict__ vals,
                                                       unsigned int* __restrict__ flags,
                                                       float* __restrict__ out) {
    __shared__ __align__(16) float E[EB];    // local prefS (extended)
    __shared__ __align__(16) float Am[TSZ];  // a in tile
    __shared__ __align__(16) float PU[TSZ];  // local prefix of U = a*(1+E[x+82])
    __shared__ __align__(16) float PV[TSZ];  // local prefix of V = a*(1-E[x+109])
    __shared__ __align__(16) float PA[TSZ];  // local prefix of a
    __shared__ float AH[76], AF[75];
    __shared__ float cfU[76], cfA[76], cbV[75], cbA[75];
    __shared__ double scr[NW];
    __shared__ double sBuf[CT];

    const int bc = blockIdx.x;
    const int b = bc / CT, c = bc % CT;
    const int t_start = c * TSZ;
    const int tid = threadIdx.x, lane = tid & 63, wid = tid >> 6;
    const int x0 = tid * IT;

    const double kd = (double)kern[0];
    const float* __restrict__ cp = conc + (size_t)b * LSEQ * NF;
    float* __restrict__ op = out + (size_t)b * NF * LSEQ;
    const float4* __restrict__ p4 = (const float4*)(cp + (size_t)(t_start + x0) * NF);

    // ---- main tile load ----
    float av[IT], Sv[IT];
    {
        float4 q[9];
        #pragma unroll
        for (int m = 0; m < 9; ++m) q[m] = p4[m];
        #pragma unroll
        for (int i = 0; i < IT; ++i) {
            float s = 0.f;
            #pragma unroll
            for (int cc2 = 0; cc2 < 9; ++cc2) {
                int idx = 9 * i + cc2;
                float val = f4c(q[idx >> 2], idx & 3);
                if (cc2 == 0) av[i] = val;
                s += val;
            }
            Sv[i] = s;
            Am[x0 + i] = av[i];
        }
    }

    // ---- scan 1: S -> local prefS; publish tile sum immediately ----
    double incl[IT], run = 0.0;
    #pragma unroll
    for (int i = 0; i < IT; ++i) { run += (double)Sv[i]; incl[i] = run; }
    double bT;   // this tile's S-sum
    double excl = block_scan(run, lane, wid, scr, &bT);
    if (tid == 0) {
        __hip_atomic_store(&vals[bc], (unsigned long long)__double_as_longlong(bT),
                           __ATOMIC_RELAXED, __HIP_MEMORY_SCOPE_AGENT);
        __hip_atomic_store(&flags[bc], 1u, __ATOMIC_RELEASE, __HIP_MEMORY_SCOPE_AGENT);
    }
    {
        float4 w = make_float4((float)(excl + incl[0]), (float)(excl + incl[1]),
                               (float)(excl + incl[2]), (float)(excl + incl[3]));
        *(float4*)&E[EOFF + x0] = w;
    }

    // ---- halo raw loads (zero-padded outside [0,LSEQ)) ----
    if (tid < EOFF) {                        // S back-halo raw -> E[0..96)
        int t = t_start - EOFF + tid;
        float s = 0.f;
        if (t >= 0) {
            const float* r = cp + (size_t)t * NF;
            #pragma unroll
            for (int m = 0; m < 9; ++m) s += r[m];
        }
        E[tid] = s;
    } else if (tid >= 96 && tid < 184) {     // S fwd-halo raw -> E[96+TSZ..+88)
        int y = tid - 96;
        int t = t_start + TSZ + y;
        float s = 0.f;
        if (t < LSEQ) {
            const float* r = cp + (size_t)t * NF;
            #pragma unroll
            for (int m = 0; m < 9; ++m) s += r[m];
        }
        E[EOFF + TSZ + y] = s;
    } else if (tid >= 192 && tid < 268) {    // a back-halo
        int i = tid - 192;
        int t = t_start - 76 + i;
        AH[i] = (t >= 0) ? cp[(size_t)t * NF] : 0.f;
    } else if (tid >= 272 && tid < 347) {    // a fwd-halo
        int y = tid - 272;
        int t = t_start + TSZ + y;
        AF[y] = (t < LSEQ) ? cp[(size_t)t * NF] : 0.f;
    }
    __syncthreads();

    // ---- halo local prefixes (offset-free): prefS(pos) = offsetS + E[idx] ----
    double hbv = 0.0, hfv = 0.0;
    if (tid < EOFF) {
        double acc = 0.0;
        for (int s2 = tid + 1; s2 < EOFF; ++s2) acc += (double)E[s2];
        hbv = -acc;
    } else if (tid >= 96 && tid < 184) {
        int y = tid - 96;
        double acc = 0.0;
        for (int s2 = 0; s2 <= y; ++s2) acc += (double)E[EOFF + TSZ + s2];
        hfv = bT + acc;
    }
    __syncthreads();
    if (tid < EOFF) E[tid] = (float)hbv;
    else if (tid >= 96 && tid < 184) E[EOFF + TSZ + (tid - 96)] = (float)hfv;
    __syncthreads();

    // ---- scans 2-4: U, V, A (all offset-free) ----
    double dmy;
    run = 0.0;
    #pragma unroll
    for (int i = 0; i < IT; ++i) {
        run += (double)av[i] * (1.0 + (double)E[x0 + i + 82]);
        incl[i] = run;
    }
    excl = block_scan(run, lane, wid, scr, &dmy);
    {
        float4 w = make_float4((float)(excl + incl[0]), (float)(excl + incl[1]),
                               (float)(excl + incl[2]), (float)(excl + incl[3]));
        *(float4*)&PU[x0] = w;
    }

    run = 0.0;
    #pragma unroll
    for (int i = 0; i < IT; ++i) {
        run += (double)av[i] * (1.0 - (double)E[x0 + i + 109]);
        incl[i] = run;
    }
    excl = block_scan(run, lane, wid, scr, &dmy);
    {
        float4 w = make_float4((float)(excl + incl[0]), (float)(excl + incl[1]),
                               (float)(excl + incl[2]), (float)(excl + incl[3]));
        *(float4*)&PV[x0] = w;
    }

    run = 0.0;
    #pragma unroll
    for (int i = 0; i < IT; ++i) { run += (double)av[i]; incl[i] = run; }
    excl = block_scan(run, lane, wid, scr, &dmy);
    {
        float4 w = make_float4((float)(excl + incl[0]), (float)(excl + incl[1]),
                               (float)(excl + incl[2]), (float)(excl + incl[3]));
        *(float4*)&PA[x0] = w;
    }
    __syncthreads();

    // ---- boundary windows: direct 60-term dots, two components each ----
    if (tid < 76) {
        int x = tid;
        double aU = 0.0, aA = 0.0;
        for (int j = x - 75; j <= x - 16; ++j) {
            float aj = (j >= 0) ? Am[j] : AH[j + 76];
            aU += (double)aj * (1.0 + (double)E[j + 82]);
            aA += (double)aj;
        }
        cfU[x] = (float)aU; cfA[x] = (float)aA;
    }
    if (tid >= 256 && tid < 331) {
        int tb = tid - 256;
        int x = TSZ - 75 + tb;
        double aV = 0.0, aA = 0.0;
        for (int u = x + 16; u <= x + 75; ++u) {
            float au = (u < TSZ) ? Am[u] : AF[u - TSZ];
            aV += (double)au * (1.0 - (double)E[u + 109]);
            aA += (double)au;
        }
        cbV[tb] = (float)aV; cbA[tb] = (float)aA;
    }

    // ---- exchange tile sums (publish happened long ago; spin is short) ----
    if (tid < CT) {
        while (__hip_atomic_load(&flags[b * CT + tid], __ATOMIC_ACQUIRE,
                                 __HIP_MEMORY_SCOPE_AGENT) != 1u) {
            __builtin_amdgcn_s_sleep(1);
        }
        unsigned long long uv = __hip_atomic_load(&vals[b * CT + tid], __ATOMIC_RELAXED,
                                                  __HIP_MEMORY_SCOPE_AGENT);
        sBuf[tid] = __longlong_as_double((long long)uv);
    }
    __syncthreads();

    double offsetS = 0.0, totS = 0.0;
    #pragma unroll
    for (int cc = 0; cc < CT; ++cc) {
        double v = sBuf[cc];
        if (cc < c) offsetS += v;
        totS += v;
    }
    const double wQoff = totS - offsetS;
    const float invZ1 = (float)(1.0 / (1.0 + totS));

    // ---- epilogue row 0 ----
    float fo[IT];
    #pragma unroll
    for (int i = 0; i < IT; ++i) {
        int x = x0 + i;
        float v = av[i];
        double cf, cb;
        if (x < 76) cf = kd * (double)v * ((double)cfU[x] + offsetS * (double)cfA[x]);
        else        cf = kd * (double)v * (((double)PU[x - 16] - (double)PU[x - 76])
                                 + offsetS * ((double)PA[x - 16] - (double)PA[x - 76]));
        if (x >= TSZ - 75) {
            int tb = x - (TSZ - 75);
            cb = kd * (double)v * ((double)cbV[tb] + wQoff * (double)cbA[tb]);
        } else {
            cb = kd * (double)v * (((double)PV[x + 75] - (double)PV[x + 15])
                           + wQoff * ((double)PA[x + 75] - (double)PA[x + 15]));
        }
        float adjv = (v > 1e-13f) ? v : (v + 1.0f);
        float f = ((float)cf * v + v * (float)cb + v * v) / adjv * invZ1;
        fo[i] = fminf(fmaxf(f, 0.0f), 0.9999f);
    }
    *(float4*)(op + t_start + x0) = make_float4(fo[0], fo[1], fo[2], fo[3]);

    // ---- rows 1..8: v^2/adj(v)/Z1 (re-read input; cache-hit) ----
    {
        float4 q[9];
        #pragma unroll
        for (int m = 0; m < 9; ++m) q[m] = p4[m];
        #pragma unroll
        for (int r = 1; r < 9; ++r) {
            float4 w;
            float* wp = (float*)&w;
            #pragma unroll
            for (int i = 0; i < IT; ++i) {
                int idx = 9 * i + r;
                float v = f4c(q[idx >> 2], idx & 3);
                float adjv = (v > 1e-13f) ? v : (v + 1.0f);
                float f = v * v / adjv * invZ1;
                wp[i] = fminf(fmaxf(f, 0.0f), 0.9999f);
            }
            *(float4*)(op + (size_t)r * LSEQ + t_start + x0) = w;
        }
    }
}

extern "C" void kernel_launch(void* const* d_in, const int* in_sizes, int n_in,
                              void* d_out, int out_size, void* d_ws, size_t ws_size,
                              hipStream_t stream) {
    const float* conc = (const float*)d_in[0];
    const float* kern = (const float*)d_in[1];
    float* out = (float*)d_out;
    unsigned long long* vals = (unsigned long long*)d_ws;
    unsigned int* flags = (unsigned int*)((char*)d_ws + 8192);
    int B = in_sizes[0] / (LSEQ * NF);
    hipLaunchKernelGGL(kenneth_fused, dim3(B * CT), dim3(NT), 0, stream,
                       conc, kern, vals, flags, out);
}

// Round 4
// 99.832 us; speedup vs baseline: 1.1394x; 1.1394x over previous
//
#include <hip/hip_runtime.h>

#define LSEQ 8192
#define NF 9
#define CT 8            // tiles per batch
#define TSZ 1024        // tile size
#define NT 256          // threads per block
#define IT 4            // positions per thread
#define NW 4            // waves per block
#define EOFF 96         // E[i] = local prefS(t0g - EOFF + i)
#define EB (EOFF + TSZ + 88)   // 1208
#define PQB (TSZ + 60)         // Pfa/Qba array size (max idx 1083)

__device__ __forceinline__ float f4c(const float4& v, int c) {
    return c == 0 ? v.x : c == 1 ? v.y : c == 2 ? v.z : v.w;
}

// ---------------- K1: per-tile sum of row-sums S ----------------
__global__ __launch_bounds__(NT) void k1_sums(const float* __restrict__ conc,
                                              double* __restrict__ ws) {
    __shared__ double wsum[NW];
    const int bc = blockIdx.x;
    const int b = bc / CT, c = bc % CT;
    const int tid = threadIdx.x, lane = tid & 63, wid = tid >> 6;
    const float4* p4 = (const float4*)(conc + (size_t)b * LSEQ * NF
                                       + (size_t)(c * TSZ + tid * IT) * NF);
    float s = 0.f;
    #pragma unroll
    for (int m = 0; m < 9; ++m) { float4 q = p4[m]; s += (q.x + q.y) + (q.z + q.w); }
    double tot = (double)s;
    #pragma unroll
    for (int off = 32; off > 0; off >>= 1) tot += __shfl_down(tot, (unsigned)off, 64);
    if (lane == 0) wsum[wid] = tot;
    __syncthreads();
    if (tid == 0) {
        double t2 = 0.0;
        #pragma unroll
        for (int w = 0; w < NW; ++w) t2 += wsum[w];
        ws[bc] = t2;
    }
}

// ---------------- K2: everything else ----------------
__global__ __launch_bounds__(NT, 4) void k2_main(const float* __restrict__ conc,
                                                 const float* __restrict__ kern,
                                                 const double* __restrict__ ws,
                                                 float* __restrict__ out) {
    __shared__ __align__(16) float E[EB];     // extended prefS (local), f32
    __shared__ __align__(16) float Pfa[PQB];  // Pf[j] at idx j+75, j in [-75, TSZ-16)
    __shared__ __align__(16) float Qba[PQB];  // Qb[u] at idx u-16, u in [16, TSZ+75)
    __shared__ float Ah[76], Af[75];
    __shared__ double scr[NW];

    const int bc = blockIdx.x;
    const int b = bc / CT, c = bc % CT;
    const int t0g = c * TSZ;
    const int tid = threadIdx.x, lane = tid & 63, wid = tid >> 6;
    const int x0 = tid * IT;

    // tile sums (uniform -> scalar loads)
    double offS = 0.0, totS = 0.0;
    const double bT = ws[bc];
    #pragma unroll
    for (int cc = 0; cc < CT; ++cc) {
        double v = ws[b * CT + cc];
        if (cc < c) offS += v;
        totS += v;
    }
    const float kf = kern[0];
    const float invZ1 = (float)(1.0 / (1.0 + totS));

    const float* __restrict__ cp = conc + (size_t)b * LSEQ * NF;
    float* __restrict__ op = out + (size_t)b * NF * LSEQ;
    const float4* __restrict__ p4 = (const float4*)(cp + (size_t)(t0g + x0) * NF);

    // ---- issue all global loads up front ----
    float4 q[9];
    #pragma unroll
    for (int m = 0; m < 9; ++m) q[m] = p4[m];

    float hs = 0.f, hcol0 = 0.f;
    if (tid < 184) {
        int t = (tid < 96) ? (t0g - 96 + tid) : (t0g + TSZ + (tid - 96));
        if (t >= 0 && t < LSEQ) {
            const float* r = cp + (size_t)t * NF;
            float s0 = r[0];
            hcol0 = s0;
            float ss = s0;
            #pragma unroll
            for (int m = 1; m < 9; ++m) ss += r[m];
            hs = ss;
        }
    }

    // ---- av, Sv; rows 1..8 stored immediately ----
    float av[IT], Sv[IT];
    #pragma unroll
    for (int i = 0; i < IT; ++i) {
        float s = 0.f;
        #pragma unroll
        for (int cc2 = 0; cc2 < 9; ++cc2) {
            int idx = 9 * i + cc2;
            float val = f4c(q[idx >> 2], idx & 3);
            if (cc2 == 0) av[i] = val;
            s += val;
        }
        Sv[i] = s;
    }
    #pragma unroll
    for (int r = 1; r < 9; ++r) {
        float4 w;
        float* wp = (float*)&w;
        #pragma unroll
        for (int i = 0; i < IT; ++i) {
            int idx = 9 * i + r;
            float v = f4c(q[idx >> 2], idx & 3);
            float adjv = (v > 1e-13f) ? v : (v + 1.0f);
            float f = v * v / adjv * invZ1;
            wp[i] = fminf(fmaxf(f, 0.0f), 0.9999f);
        }
        *(float4*)(op + (size_t)r * LSEQ + t0g + x0) = w;
    }

    // ---- raw halos to LDS ----
    if (tid < 96) E[tid] = hs;
    else if (tid < 184) E[EOFF + TSZ + (tid - 96)] = hs;
    if (tid >= 20 && tid < 96) Ah[tid - 20] = hcol0;       // a(t0g-76+i)
    if (tid >= 96 && tid < 171) Af[tid - 96] = hcol0;      // a(t0g+TSZ+y)

    // ---- scan 1 (the only block scan): S -> local prefS ----
    double incl[IT];
    double run = 0.0;
    #pragma unroll
    for (int i = 0; i < IT; ++i) { run += (double)Sv[i]; incl[i] = run; }
    double v = run;
    #pragma unroll
    for (int off = 1; off < 64; off <<= 1) {
        double n = __shfl_up(v, (unsigned)off, 64);
        if (lane >= off) v += n;
    }
    if (lane == 63) scr[wid] = v;
    __syncthreads();                                   // B1
    double wOff = 0.0;
    #pragma unroll
    for (int w = 0; w < NW; ++w) if (w < wid) wOff += scr[w];
    double excl = wOff + (v - run);
    {
        float4 w = make_float4((float)(excl + incl[0]), (float)(excl + incl[1]),
                               (float)(excl + incl[2]), (float)(excl + incl[3]));
        *(float4*)&E[EOFF + x0] = w;
    }

    // halo local prefixes (prefS_global = offS + value)
    double hpref = 0.0;
    if (tid < 96) {
        double acc = 0.0;
        for (int s2 = tid + 1; s2 < 96; ++s2) acc += (double)E[s2];
        hpref = -acc;
    } else if (tid < 184) {
        int y = tid - 96;
        double acc = 0.0;
        for (int s2 = 0; s2 <= y; ++s2) acc += (double)E[EOFF + TSZ + s2];
        hpref = bT + acc;
    }
    __syncthreads();                                   // B2
    if (tid < 96) E[tid] = (float)hpref;
    else if (tid < 184) E[EOFF + TSZ + (tid - 96)] = (float)hpref;
    __syncthreads();                                   // B3

    // ---- build term arrays: Pf[j]=a_j*Z(j-14), Qb[u]=a_u*W(u+14) ----
    const double zoff = 1.0 + offS;
    const double woff = 1.0 + totS - offS;
    {
        float pv[IT], qv[IT];
        #pragma unroll
        for (int i = 0; i < IT; ++i) {
            int x = x0 + i;
            pv[i] = av[i] * (float)(zoff + (double)E[EOFF + x - 14]);
            qv[i] = av[i] * (float)(woff - (double)E[EOFF + x + 13]);
        }
        #pragma unroll
        for (int i = 0; i < IT; ++i) Pfa[x0 + 75 + i] = pv[i];
        if (x0 >= 16) {
            *(float4*)&Qba[x0 - 16] = make_float4(qv[0], qv[1], qv[2], qv[3]);
        } else {
            #pragma unroll
            for (int i = 0; i < IT; ++i) if (x0 + i >= 16) Qba[x0 + i - 16] = qv[i];
        }
    }
    if (tid < 75) {
        // Pf halo: j = tid-75 in [-75,0): idx tid; E idx = EOFF + j - 14 = tid + 7
        Pfa[tid] = Ah[tid + 1] * (float)(zoff + (double)E[tid + 7]);
        // Qb halo: u = TSZ + tid: idx TSZ-16+tid; E idx = EOFF + TSZ + tid + 13
        Qba[TSZ - 16 + tid] = Af[tid] * (float)(woff - (double)E[EOFF + TSZ + tid + 13]);
    }
    __syncthreads();                                   // B4

    // ---- direct sliding windows (aligned b128 reads) ----
    float cfw[IT], cbw[IT];
    {
        const float4* Pf4 = (const float4*)&Pfa[x0];
        float4 pa = Pf4[0], pb = Pf4[15];
        float4 s4 = pa;
        #pragma unroll
        for (int m = 1; m < 15; ++m) { float4 t = Pf4[m]; s4.x += t.x; s4.y += t.y; s4.z += t.z; s4.w += t.w; }
        cfw[0] = (s4.x + s4.y) + (s4.z + s4.w);
        cfw[1] = cfw[0] - pa.x + pb.x;
        cfw[2] = cfw[1] - pa.y + pb.y;
        cfw[3] = cfw[2] - pa.z + pb.z;
    }
    {
        const float4* Qb4 = (const float4*)&Qba[x0];
        float4 pa = Qb4[0], pb = Qb4[15];
        float4 s4 = pa;
        #pragma unroll
        for (int m = 1; m < 15; ++m) { float4 t = Qb4[m]; s4.x += t.x; s4.y += t.y; s4.z += t.z; s4.w += t.w; }
        cbw[0] = (s4.x + s4.y) + (s4.z + s4.w);
        cbw[1] = cbw[0] - pa.x + pb.x;
        cbw[2] = cbw[1] - pa.y + pb.y;
        cbw[3] = cbw[2] - pa.z + pb.z;
    }

    // ---- row 0 ----
    float fo[IT];
    #pragma unroll
    for (int i = 0; i < IT; ++i) {
        float a = av[i];
        float cf = kf * a * cfw[i];
        float cb = kf * a * cbw[i];
        float adjv = (a > 1e-13f) ? a : (a + 1.0f);
        float f = (cf * a + a * cb + a * a) / adjv * invZ1;
        fo[i] = fminf(fmaxf(f, 0.0f), 0.9999f);
    }
    *(float4*)(op + t0g + x0) = make_float4(fo[0], fo[1], fo[2], fo[3]);
}

extern "C" void kernel_launch(void* const* d_in, const int* in_sizes, int n_in,
                              void* d_out, int out_size, void* d_ws, size_t ws_size,
                              hipStream_t stream) {
    const float* conc = (const float*)d_in[0];
    const float* kern = (const float*)d_in[1];
    float* out = (float*)d_out;
    double* wsd = (double*)d_ws;
    int B = in_sizes[0] / (LSEQ * NF);
    hipLaunchKernelGGL(k1_sums, dim3(B * CT), dim3(NT), 0, stream, conc, wsd);
    hipLaunchKernelGGL(k2_main, dim3(B * CT), dim3(NT), 0, stream, conc, kern, wsd, out);
}